// Round 4
// baseline (621.835 us; speedup 1.0000x reference)
//
#include <hip/hip_runtime.h>

#define NUM_K   4096
#define CDIM    64
#define HWDIM   4096            // 64*64
#define NVEC    65536           // 16 * 64 * 64
#define CHW     (CDIM * HWDIM)  // 262144
#define TAU     4e-3f           // rescue margin; >> bf16x3 split error (~5e-5 RMS)

// ---- output layout (floats, concatenated in reference return order) ----
#define O_Q     0               // quantized_ste  [16,64,64,64] = 4194304
#define O_LOSS  4194304         // scalar
#define O_IDX   4194305         // encoding_indices [16,64,64] = 65536 (as float)
#define O_W     4259841         // new_weight   [4096,64] = 262144
#define O_CS    4521985         // new_cluster_size [4096]
#define O_EW    4526081         // new_ema_w    [4096,64] = 262144

// ---- workspace layout (floats) ----
#define W_WSQ    0               // 4096
#define W_BIDX   4096            // best idx int[65536]
#define W_CNT    69632           // counts [4096]
#define W_LOSS   73728           // 1
#define W_N      73729           // 1
#define W_RCNT   73730           // 1 (int)
#define W_DW     73732           // dw [262144]; rescan list overlays (dead before dw zeroed)

typedef unsigned long long u64;
typedef __bf16 bf16x8 __attribute__((ext_vector_type(8)));
typedef float  f32x4  __attribute__((ext_vector_type(4)));

__device__ __forceinline__ unsigned f2ord(float f) {
    unsigned u = __float_as_uint(f);
    return (u & 0x80000000u) ? ~u : (u | 0x80000000u);  // monotone for all finite floats
}

// Per codebook row: wsq (fp32, exact) + bf16 hi/lo split copies.
__global__ void __launch_bounds__(256)
prep_kernel(const float* __restrict__ w, float* __restrict__ wsq,
            __bf16* __restrict__ wh, __bf16* __restrict__ wl) {
    int wv = threadIdx.x >> 6, lane = threadIdx.x & 63;
    int row = blockIdx.x * 4 + wv;
    float v = w[row * CDIM + lane];
    __bf16 h = (__bf16)v;
    __bf16 l = (__bf16)(v - (float)h);     // x - hi is exact in fp32 (two-term split)
    wh[row * CDIM + lane] = h;
    wl[row * CDIM + lane] = l;
    float sq = v * v;
#pragma unroll
    for (int m = 1; m < 64; m <<= 1) sq += __shfl_xor(sq, m, 64);
    if (lane == 0) wsq[row] = sq;
}

// Fused bf16x3-split MFMA GEMM + argmin with top-2 margin tracking.
// Block = 64 vectors (4 waves x 16 vectors); each wave scans all 4096 codes.
// mfma_f32_16x16x32_bf16: A[m=lane&15][k=(lane>>4)*8+j]; C/D col=lane&15,
// row=(lane>>4)*4+reg (guide-verified layouts).
__global__ void __launch_bounds__(256)
argmin_mfma(const float* __restrict__ x,
            const __bf16* __restrict__ wh_g, const __bf16* __restrict__ wl_g,
            const float* __restrict__ wsq_g,
            int* __restrict__ best_idx, int* __restrict__ rcnt,
            int* __restrict__ rlist) {
    __shared__ __bf16 xs_h[64 * 72];   // [v][c], stride 72 for 16B-aligned frag reads
    __shared__ __bf16 xs_l[64 * 72];
    __shared__ float  wsq_s[NUM_K];    // 16 KB

    int t = threadIdx.x;
    int wv = t >> 6, lane = t & 63;
    int n0 = blockIdx.x * 64;
    int b = n0 >> 12, hw0 = n0 & (HWDIM - 1);

    // stage x block -> LDS as bf16 hi/lo (transposed, coalesced global reads)
#pragma unroll
    for (int j = 0; j < 16; ++j) {
        int c = wv * 16 + j;
        float v = x[b * CHW + c * HWDIM + hw0 + lane];
        __bf16 h = (__bf16)v;
        xs_h[lane * 72 + c] = h;
        xs_l[lane * 72 + c] = (__bf16)(v - (float)h);
    }
    for (int i = t; i < NUM_K; i += 256) wsq_s[i] = wsq_g[i];
    __syncthreads();

    int nn = lane & 15, q4 = lane >> 4;
    // A-frags: this wave's 16 vectors, register-resident for the whole k-loop
    const __bf16* xrh = xs_h + (wv * 16 + nn) * 72 + 8 * q4;
    const __bf16* xrl = xs_l + (wv * 16 + nn) * 72 + 8 * q4;
    bf16x8 ah0 = *(const bf16x8*)(xrh);        // c chunk 0..31
    bf16x8 ah1 = *(const bf16x8*)(xrh + 32);   // c chunk 32..63
    bf16x8 al0 = *(const bf16x8*)(xrl);
    bf16x8 al1 = *(const bf16x8*)(xrl + 32);

    float b1[4] = {3.4e38f, 3.4e38f, 3.4e38f, 3.4e38f};
    float b2[4] = {3.4e38f, 3.4e38f, 3.4e38f, 3.4e38f};
    int   i1[4] = {0, 0, 0, 0};

#pragma unroll 2
    for (int kt = 0; kt < NUM_K / 16; ++kt) {
        int k0 = kt * 16;
        const __bf16* brh = wh_g + (k0 + nn) * CDIM + 8 * q4;
        const __bf16* brl = wl_g + (k0 + nn) * CDIM + 8 * q4;
        bf16x8 bh0 = *(const bf16x8*)(brh);
        bf16x8 bh1 = *(const bf16x8*)(brh + 32);
        bf16x8 bl0 = *(const bf16x8*)(brl);
        bf16x8 bl1 = *(const bf16x8*)(brl + 32);

        f32x4 acc = {0.f, 0.f, 0.f, 0.f};
        acc = __builtin_amdgcn_mfma_f32_16x16x32_bf16(ah0, bh0, acc, 0, 0, 0);
        acc = __builtin_amdgcn_mfma_f32_16x16x32_bf16(ah1, bh1, acc, 0, 0, 0);
        acc = __builtin_amdgcn_mfma_f32_16x16x32_bf16(ah0, bl0, acc, 0, 0, 0);
        acc = __builtin_amdgcn_mfma_f32_16x16x32_bf16(ah1, bl1, acc, 0, 0, 0);
        acc = __builtin_amdgcn_mfma_f32_16x16x32_bf16(al0, bh0, acc, 0, 0, 0);
        acc = __builtin_amdgcn_mfma_f32_16x16x32_bf16(al1, bh1, acc, 0, 0, 0);

        float wsqv = wsq_s[k0 + nn];
        int kcode = k0 + nn;
#pragma unroll
        for (int r = 0; r < 4; ++r) {
            float s = fmaf(acc[r], -2.0f, wsqv);
            float tt = fmaxf(b1[r], s);
            b2[r] = fminf(b2[r], tt);          // running second-best
            if (s < b1[r]) i1[r] = kcode;      // strict < => first-min in k order
            b1[r] = fminf(b1[r], s);
        }
    }

    // cross-lane top-2 merge over the 16 code-classes (lanes sharing q4)
#pragma unroll
    for (int m = 1; m < 16; m <<= 1) {
#pragma unroll
        for (int r = 0; r < 4; ++r) {
            float ob1 = __shfl_xor(b1[r], m, 64);
            int   oi1 = __shfl_xor(i1[r], m, 64);
            float ob2 = __shfl_xor(b2[r], m, 64);
            float tt = fmaxf(b1[r], ob1);
            b2[r] = fminf(fminf(b2[r], ob2), tt);
            if (ob1 < b1[r]) i1[r] = oi1;      // exact ties get rescued anyway
            b1[r] = fminf(b1[r], ob1);
        }
    }
    if (nn == 0) {
#pragma unroll
        for (int r = 0; r < 4; ++r) {
            int v = n0 + wv * 16 + q4 * 4 + r;
            best_idx[v] = i1[r];
            if (b2[r] - b1[r] < TAU) {         // ambiguous at bf16x3 precision
                int p = atomicAdd(rcnt, 1);
                rlist[p] = v;
            }
        }
    }
}

// Exact fp32 re-argmin for flagged (near-tie) vectors. Typically <100 vectors.
__global__ void __launch_bounds__(256)
rescue_kernel(const float* __restrict__ x, const float* __restrict__ w,
              const float* __restrict__ wsq, int* __restrict__ best_idx,
              const int* __restrict__ rcnt, const int* __restrict__ rlist) {
    __shared__ float xv[CDIM];
    __shared__ u64 rk[256];
    int t = threadIdx.x;
    int cnt = *rcnt;
    for (int i = blockIdx.x; i < cnt; i += gridDim.x) {
        int n = rlist[i];
        int b = n >> 12, hw = n & (HWDIM - 1);
        if (t < CDIM) xv[t] = x[b * CHW + t * HWDIM + hw];
        __syncthreads();
        u64 local = ~0ull;
        for (int k = t; k < NUM_K; k += 256) {
            const float* wr = w + k * CDIM;
            float d0 = 0.f, d1 = 0.f, d2 = 0.f, d3 = 0.f;
#pragma unroll
            for (int c = 0; c < CDIM; c += 4) {
                d0 = fmaf(xv[c + 0], wr[c + 0], d0);
                d1 = fmaf(xv[c + 1], wr[c + 1], d1);
                d2 = fmaf(xv[c + 2], wr[c + 2], d2);
                d3 = fmaf(xv[c + 3], wr[c + 3], d3);
            }
            float s = fmaf((d0 + d1) + (d2 + d3), -2.0f, wsq[k]);
            u64 key = ((u64)f2ord(s) << 32) | (unsigned)k;   // lower k wins ties
            local = local < key ? local : key;
        }
        rk[t] = local;
        __syncthreads();
        for (int s = 128; s > 0; s >>= 1) {
            if (t < s) rk[t] = rk[t] < rk[t + s] ? rk[t] : rk[t + s];
            __syncthreads();
        }
        if (t == 0) best_idx[n] = (int)(rk[0] & 0xFFFFFFFFu);
        __syncthreads();
    }
}

// Gather quantized, STE output, loss partials, histogram + coalesced dw scatter.
__global__ void __launch_bounds__(256)
assign_kernel(const float* __restrict__ x, const float* __restrict__ w,
              const int* __restrict__ best_idx,
              float* __restrict__ out, float* __restrict__ counts,
              float* __restrict__ dw, float* __restrict__ loss_acc) {
    __shared__ float xs[64][CDIM + 1];
    __shared__ int   sidx[64];
    __shared__ float red[256];

    int t  = threadIdx.x;
    int n0 = blockIdx.x * 64;
    int b  = n0 >> 12;
    int hw0 = n0 & (HWDIM - 1);
    const float* xbase = x + b * CHW + hw0;

    if (t < 64) {
        int idx = best_idx[n0 + t];
        sidx[t] = idx;
        out[O_IDX + n0 + t] = (float)idx;
        atomicAdd(&counts[idx], 1.0f);
    }

    int lane = t & 63, wv = t >> 6;
#pragma unroll
    for (int j = 0; j < 16; ++j) {
        int c = wv + j * 4;
        xs[lane][c] = xbase[c * HWDIM + lane];
    }
    __syncthreads();

    float lsum = 0.f;
#pragma unroll
    for (int j = 0; j < 16; ++j) {
        int c = wv + j * 4;
        float xv = xs[lane][c];
        float qv = w[sidx[lane] * CDIM + c];
        float d = qv - xv;
        out[O_Q + b * CHW + c * HWDIM + hw0 + lane] = xv + d;
        lsum = fmaf(d, d, lsum);
    }
    red[t] = lsum;
    __syncthreads();
    for (int s = 128; s > 0; s >>= 1) {
        if (t < s) red[t] += red[t + s];
        __syncthreads();
    }
    if (t == 0) atomicAdd(loss_acc, red[0]);

    for (int i = 0; i < 16; ++i) {
        int nl = wv * 16 + i;
        atomicAdd(&dw[sidx[nl] * CDIM + lane], xs[nl][lane]);  // wave-coalesced row
    }
}

__global__ void __launch_bounds__(256)
finalize_cs(const float* __restrict__ ecs, const float* __restrict__ counts,
            float* __restrict__ out, const float* __restrict__ loss_acc,
            float* __restrict__ nptr) {
    int t = threadIdx.x;
    float local = 0.f;
    for (int k = t; k < NUM_K; k += 256) {
        float ncs = 0.99f * ecs[k] + 0.01f * counts[k];
        out[O_CS + k] = ncs;
        local += ncs;
    }
    __shared__ float red[256];
    red[t] = local;
    __syncthreads();
    for (int s = 128; s > 0; s >>= 1) {
        if (t < s) red[t] += red[t + s];
        __syncthreads();
    }
    if (t == 0) {
        nptr[0] = red[0];
        out[O_LOSS] = 0.25f * loss_acc[0] / 4194304.0f;
    }
}

__global__ void __launch_bounds__(256)
finalize_w(const float* __restrict__ ema_w, const float* __restrict__ dw,
           float* __restrict__ out, const float* __restrict__ nptr) {
    int e = blockIdx.x * 256 + threadIdx.x;
    int k = e >> 6;
    float n = nptr[0];
    float ncs = out[O_CS + k];
    float cs = (ncs + 1e-5f) / (n + NUM_K * 1e-5f) * n;
    float ew = 0.99f * ema_w[e] + 0.01f * dw[e];
    out[O_EW + e] = ew;
    out[O_W + e] = ew / cs;
}

extern "C" void kernel_launch(void* const* d_in, const int* in_sizes, int n_in,
                              void* d_out, int out_size, void* d_ws, size_t ws_size,
                              hipStream_t stream) {
    const float* x     = (const float*)d_in[0];
    const float* w     = (const float*)d_in[1];
    const float* ecs   = (const float*)d_in[2];
    const float* ema_w = (const float*)d_in[3];
    float* out = (float*)d_out;
    float* ws  = (float*)d_ws;

    float* wsq    = ws + W_WSQ;
    int*   bidx   = (int*)(ws + W_BIDX);
    float* counts = ws + W_CNT;
    float* loss_a = ws + W_LOSS;
    float* nptr   = ws + W_N;
    int*   rcnt   = (int*)(ws + W_RCNT);
    float* dw     = ws + W_DW;
    int*   rlist  = (int*)(ws + W_DW);     // overlays dw; dead before dw is zeroed

    // bf16 hi/lo codebook scratch lives in O_Q (fully overwritten by assign later)
    __bf16* wh = (__bf16*)out;             // 512 KB
    __bf16* wl = wh + NUM_K * CDIM;        // 512 KB

    hipMemsetAsync(counts, 0, 4099 * sizeof(float), stream);   // counts+loss+n+rcnt

    prep_kernel<<<NUM_K / 4, 256, 0, stream>>>(w, wsq, wh, wl);
    argmin_mfma<<<NVEC / 64, 256, 0, stream>>>(x, wh, wl, wsq, bidx, rcnt, rlist);
    rescue_kernel<<<256, 256, 0, stream>>>(x, w, wsq, bidx, rcnt, rlist);

    hipMemsetAsync(dw, 0, (size_t)CHW * sizeof(float), stream);  // after rlist is dead

    assign_kernel<<<NVEC / 64, 256, 0, stream>>>(x, w, bidx, out, counts, dw, loss_a);
    finalize_cs<<<1, 256, 0, stream>>>(ecs, counts, out, loss_a, nptr);
    finalize_w<<<CHW / 256, 256, 0, stream>>>(ema_w, dw, out, nptr);
}

// Round 5
// 311.250 us; speedup vs baseline: 1.9979x; 1.9979x over previous
//
#include <hip/hip_runtime.h>

#define NUM_K   4096
#define CDIM    64
#define HWDIM   4096            // 64*64
#define NVEC    65536           // 16 * 64 * 64
#define CHW     (CDIM * HWDIM)  // 262144
#define KT      32              // codes per k-tile (2 x 16-code subtiles)
#define NKT     (NUM_K / KT)    // 128
#define TAUH    2e-3f           // rescue margin on s/2 scale == round-4's 4e-3 on s

// ---- output layout (floats, concatenated in reference return order) ----
#define O_Q     0               // quantized_ste  [16,64,64,64] = 4194304
#define O_LOSS  4194304         // scalar
#define O_IDX   4194305         // encoding_indices [16,64,64] = 65536 (as float)
#define O_W     4259841         // new_weight   [4096,64] = 262144
#define O_CS    4521985         // new_cluster_size [4096]
#define O_EW    4526081         // new_ema_w    [4096,64] = 262144

// ---- workspace layout (floats) ----
#define W_WSQ    0               // 4096
#define W_BIDX   4096            // best idx int[65536]
#define W_CNT    69632           // counts [4096]
#define W_LOSS   73728           // 1
#define W_N      73729           // 1
#define W_RCNT   73730           // 1 (int)
#define W_DW     73732           // dw [262144]; rescue list overlays (dead before dw zeroed)

typedef unsigned long long u64;
typedef __bf16 bf16x8 __attribute__((ext_vector_type(8)));
typedef float  f32x4  __attribute__((ext_vector_type(4)));

__device__ __forceinline__ unsigned f2ord(float f) {
    unsigned u = __float_as_uint(f);
    return (u & 0x80000000u) ? ~u : (u | 0x80000000u);  // monotone for all finite floats
}

// Per codebook row: wsq (fp32, exact) + bf16 hi/lo split copies (row-major).
__global__ void __launch_bounds__(256)
prep_kernel(const float* __restrict__ w, float* __restrict__ wsq,
            __bf16* __restrict__ wh, __bf16* __restrict__ wl) {
    int wv = threadIdx.x >> 6, lane = threadIdx.x & 63;
    int row = blockIdx.x * 4 + wv;
    float v = w[row * CDIM + lane];
    __bf16 h = (__bf16)v;
    __bf16 l = (__bf16)(v - (float)h);     // v - hi is exact in fp32 (two-term split)
    wh[row * CDIM + lane] = h;
    wl[row * CDIM + lane] = l;
    float sq = v * v;
#pragma unroll
    for (int m = 1; m < 64; m <<= 1) sq += __shfl_xor(sq, m, 64);
    if (lane == 0) wsq[row] = sq;
}

// Fused bf16x3-split MFMA GEMM + argmin.
// Block = 128 vectors (4 waves x 2 M-tiles of 16). Codebook streamed through a
// double-buffered 32-code LDS tile shared by all waves (m97-style K-loop:
// issue loads for kt+1, compute kt, ds_write kt+1, barrier).
// Trick: A-frags hold -x (hi/lo), acc inits to wsq/2 => MFMA output IS s/2.
// mfma_f32_16x16x32_bf16: A[m=lane&15][k=(lane>>4)*8+j]; C/D col=lane&15 (code),
// row=(lane>>4)*4+reg (vector) — layouts validated by round-4 pass.
__global__ void __launch_bounds__(256)
argmin_mfma(const float* __restrict__ x,
            const __bf16* __restrict__ wh_g, const __bf16* __restrict__ wl_g,
            const float* __restrict__ wsq_g,
            int* __restrict__ best_idx, int* __restrict__ rcnt,
            int* __restrict__ rlist) {
    __shared__ __bf16 xs_h[128 * 72];   // 18.4 KB, stride 72 => uniform-bank b128 reads
    __shared__ __bf16 xs_l[128 * 72];
    __shared__ __bf16 bs[2][4096];      // 16 KB: [buf][ sub0_hi | sub1_hi | sub0_lo | sub1_lo ]
                                        // subtile layout: elem(code r<16, ch c) at (c/8*16 + r)*8 + c%8

    int t = threadIdx.x, wv = t >> 6, lane = t & 63;
    int n0 = blockIdx.x * 128;
    int b = n0 >> 12, hw0 = n0 & (HWDIM - 1);

    // stage -x as bf16 hi/lo into LDS (coalesced 64-float rows)
#pragma unroll
    for (int half = 0; half < 2; ++half) {
        int i = half * 64 + lane;
#pragma unroll
        for (int j = 0; j < 16; ++j) {
            int c = wv * 16 + j;
            float v = -x[b * CHW + c * HWDIM + hw0 + i];
            __bf16 h = (__bf16)v;
            xs_h[i * 72 + c] = h;
            xs_l[i * 72 + c] = (__bf16)(v - (float)h);
        }
    }
    // stage B tile 0 into buf 0: thread t handles 16B chunks (hi: code t/8, ch-col t%8) and (lo: same)
    {
        int r32 = t >> 3, j = t & 7;
        int dst = ((r32 >> 4) * 1024) + (j * 16 + (r32 & 15)) * 8;
        *(bf16x8*)&bs[0][dst]        = *(const bf16x8*)(wh_g + r32 * 64 + j * 8);
        *(bf16x8*)&bs[0][2048 + dst] = *(const bf16x8*)(wl_g + r32 * 64 + j * 8);
    }
    __syncthreads();

    int nn = lane & 15, q4 = lane >> 4;
    // A-frags: 2 M-tiles, register-resident for the whole k-loop
    bf16x8 ah[2][2], al[2][2];
#pragma unroll
    for (int m = 0; m < 2; ++m) {
        const __bf16* ph = xs_h + (wv * 32 + m * 16 + nn) * 72 + q4 * 8;
        const __bf16* pl = xs_l + (wv * 32 + m * 16 + nn) * 72 + q4 * 8;
        ah[m][0] = *(const bf16x8*)ph;  ah[m][1] = *(const bf16x8*)(ph + 32);
        al[m][0] = *(const bf16x8*)pl;  al[m][1] = *(const bf16x8*)(pl + 32);
    }

    float b1[8], b2[8]; int i1[8];
#pragma unroll
    for (int s = 0; s < 8; ++s) { b1[s] = 3.4e38f; b2[s] = 3.4e38f; i1[s] = 0; }

    int stg_r32 = t >> 3, stg_j = t & 7;
    int stg_dst = ((stg_r32 >> 4) * 1024) + (stg_j * 16 + (stg_r32 & 15)) * 8;

    for (int kt = 0; kt < NKT; ++kt) {
        const __bf16* base = &bs[kt & 1][0];
        bf16x8 st0, st1;
        bool pre = (kt + 1 < NKT);
        if (pre) {   // issue global loads for next tile NOW; consume after compute
            int k0n = (kt + 1) * KT;
            st0 = *(const bf16x8*)(wh_g + (k0n + stg_r32) * 64 + stg_j * 8);
            st1 = *(const bf16x8*)(wl_g + (k0n + stg_r32) * 64 + stg_j * 8);
        }

        int k0 = kt * KT;
        float wA = 0.5f * wsq_g[k0 + nn];        // 16 KB table, L1-hot
        float wB = 0.5f * wsq_g[k0 + 16 + nn];

        int o1 = (q4 * 16 + nn) * 8, o2 = ((q4 + 4) * 16 + nn) * 8;
        bf16x8 bh0A = *(const bf16x8*)(base + o1);
        bf16x8 bh1A = *(const bf16x8*)(base + o2);
        bf16x8 bh0B = *(const bf16x8*)(base + 1024 + o1);
        bf16x8 bh1B = *(const bf16x8*)(base + 1024 + o2);
        bf16x8 bl0A = *(const bf16x8*)(base + 2048 + o1);
        bf16x8 bl1A = *(const bf16x8*)(base + 2048 + o2);
        bf16x8 bl0B = *(const bf16x8*)(base + 3072 + o1);
        bf16x8 bl1B = *(const bf16x8*)(base + 3072 + o2);

#pragma unroll
        for (int m = 0; m < 2; ++m) {
            f32x4 accA = {wA, wA, wA, wA};       // acc = wsq/2 - dot  ==  s/2
            f32x4 accB = {wB, wB, wB, wB};
            accA = __builtin_amdgcn_mfma_f32_16x16x32_bf16(ah[m][0], bh0A, accA, 0, 0, 0);
            accA = __builtin_amdgcn_mfma_f32_16x16x32_bf16(ah[m][1], bh1A, accA, 0, 0, 0);
            accA = __builtin_amdgcn_mfma_f32_16x16x32_bf16(al[m][0], bh0A, accA, 0, 0, 0);
            accA = __builtin_amdgcn_mfma_f32_16x16x32_bf16(al[m][1], bh1A, accA, 0, 0, 0);
            accA = __builtin_amdgcn_mfma_f32_16x16x32_bf16(ah[m][0], bl0A, accA, 0, 0, 0);
            accA = __builtin_amdgcn_mfma_f32_16x16x32_bf16(ah[m][1], bl1A, accA, 0, 0, 0);
            accB = __builtin_amdgcn_mfma_f32_16x16x32_bf16(ah[m][0], bh0B, accB, 0, 0, 0);
            accB = __builtin_amdgcn_mfma_f32_16x16x32_bf16(ah[m][1], bh1B, accB, 0, 0, 0);
            accB = __builtin_amdgcn_mfma_f32_16x16x32_bf16(al[m][0], bh0B, accB, 0, 0, 0);
            accB = __builtin_amdgcn_mfma_f32_16x16x32_bf16(al[m][1], bh1B, accB, 0, 0, 0);
            accB = __builtin_amdgcn_mfma_f32_16x16x32_bf16(ah[m][0], bl0B, accB, 0, 0, 0);
            accB = __builtin_amdgcn_mfma_f32_16x16x32_bf16(ah[m][1], bl1B, accB, 0, 0, 0);
#pragma unroll
            for (int r = 0; r < 4; ++r) {
                float sa = accA[r], sb = accB[r];        // codes k0+nn, k0+16+nn
                float lo = fminf(sa, sb), hi = fmaxf(sa, sb);
                int   il = (sb < sa) ? (k0 + 16 + nn) : (k0 + nn);  // tie -> lower k
                int   s8 = m * 4 + r;
                b2[s8] = fminf(fminf(b2[s8], hi), fmaxf(b1[s8], lo));
                if (lo < b1[s8]) i1[s8] = il;            // strict < => first-min in k
                b1[s8] = fminf(b1[s8], lo);
            }
        }
        if (pre) {
            __bf16* nb = &bs[(kt + 1) & 1][0];
            *(bf16x8*)(nb + stg_dst)        = st0;
            *(bf16x8*)(nb + 2048 + stg_dst) = st1;
        }
        __syncthreads();
    }

    // cross-lane merge over the 16 code-classes (lanes sharing q4)
#pragma unroll
    for (int msk = 1; msk < 16; msk <<= 1) {
#pragma unroll
        for (int s = 0; s < 8; ++s) {
            float ob1 = __shfl_xor(b1[s], msk, 64);
            float ob2 = __shfl_xor(b2[s], msk, 64);
            int   oi1 = __shfl_xor(i1[s], msk, 64);
            b2[s] = fminf(fminf(b2[s], ob2), fmaxf(b1[s], ob1));
            if (ob1 < b1[s]) i1[s] = oi1;    // exact cross-lane ties get rescued anyway
            b1[s] = fminf(b1[s], ob1);
        }
    }
    if (nn == 0) {
#pragma unroll
        for (int s = 0; s < 8; ++s) {
            int m = s >> 2, r = s & 3;
            int v = n0 + wv * 32 + m * 16 + q4 * 4 + r;
            best_idx[v] = i1[s];
            if (b2[s] - b1[s] < TAUH) {       // ambiguous at bf16x3 precision
                int p = atomicAdd(rcnt, 1);
                rlist[p] = v;
            }
        }
    }
}

// Exact fp32 re-argmin for flagged (near-tie) vectors. Typically <100 vectors.
__global__ void __launch_bounds__(256)
rescue_kernel(const float* __restrict__ x, const float* __restrict__ w,
              const float* __restrict__ wsq, int* __restrict__ best_idx,
              const int* __restrict__ rcnt, const int* __restrict__ rlist) {
    __shared__ float xv[CDIM];
    __shared__ u64 rk[256];
    int t = threadIdx.x;
    int cnt = *rcnt;
    for (int i = blockIdx.x; i < cnt; i += gridDim.x) {
        int n = rlist[i];
        int b = n >> 12, hw = n & (HWDIM - 1);
        if (t < CDIM) xv[t] = x[b * CHW + t * HWDIM + hw];
        __syncthreads();
        u64 local = ~0ull;
        for (int k = t; k < NUM_K; k += 256) {
            const float* wr = w + k * CDIM;
            float d0 = 0.f, d1 = 0.f, d2 = 0.f, d3 = 0.f;
#pragma unroll
            for (int c = 0; c < CDIM; c += 4) {
                d0 = fmaf(xv[c + 0], wr[c + 0], d0);
                d1 = fmaf(xv[c + 1], wr[c + 1], d1);
                d2 = fmaf(xv[c + 2], wr[c + 2], d2);
                d3 = fmaf(xv[c + 3], wr[c + 3], d3);
            }
            float s = fmaf((d0 + d1) + (d2 + d3), -2.0f, wsq[k]);
            u64 key = ((u64)f2ord(s) << 32) | (unsigned)k;   // lower k wins ties
            local = local < key ? local : key;
        }
        rk[t] = local;
        __syncthreads();
        for (int s = 128; s > 0; s >>= 1) {
            if (t < s) rk[t] = rk[t] < rk[t + s] ? rk[t] : rk[t + s];
            __syncthreads();
        }
        if (t == 0) best_idx[n] = (int)(rk[0] & 0xFFFFFFFFu);
        __syncthreads();
    }
}

// Gather quantized, STE output, loss partials, histogram + coalesced dw scatter.
__global__ void __launch_bounds__(256)
assign_kernel(const float* __restrict__ x, const float* __restrict__ w,
              const int* __restrict__ best_idx,
              float* __restrict__ out, float* __restrict__ counts,
              float* __restrict__ dw, float* __restrict__ loss_acc) {
    __shared__ float xs[64][CDIM + 1];
    __shared__ int   sidx[64];
    __shared__ float red[256];

    int t  = threadIdx.x;
    int n0 = blockIdx.x * 64;
    int b  = n0 >> 12;
    int hw0 = n0 & (HWDIM - 1);
    const float* xbase = x + b * CHW + hw0;

    if (t < 64) {
        int idx = best_idx[n0 + t];
        sidx[t] = idx;
        out[O_IDX + n0 + t] = (float)idx;
        atomicAdd(&counts[idx], 1.0f);
    }

    int lane = t & 63, wv = t >> 6;
#pragma unroll
    for (int j = 0; j < 16; ++j) {
        int c = wv + j * 4;
        xs[lane][c] = xbase[c * HWDIM + lane];
    }
    __syncthreads();

    float lsum = 0.f;
#pragma unroll
    for (int j = 0; j < 16; ++j) {
        int c = wv + j * 4;
        float xv = xs[lane][c];
        float qv = w[sidx[lane] * CDIM + c];
        float d = qv - xv;
        out[O_Q + b * CHW + c * HWDIM + hw0 + lane] = xv + d;
        lsum = fmaf(d, d, lsum);
    }
    red[t] = lsum;
    __syncthreads();
    for (int s = 128; s > 0; s >>= 1) {
        if (t < s) red[t] += red[t + s];
        __syncthreads();
    }
    if (t == 0) atomicAdd(loss_acc, red[0]);

    for (int i = 0; i < 16; ++i) {
        int nl = wv * 16 + i;
        atomicAdd(&dw[sidx[nl] * CDIM + lane], xs[nl][lane]);  // wave-coalesced row
    }
}

__global__ void __launch_bounds__(256)
finalize_cs(const float* __restrict__ ecs, const float* __restrict__ counts,
            float* __restrict__ out, const float* __restrict__ loss_acc,
            float* __restrict__ nptr) {
    int t = threadIdx.x;
    float local = 0.f;
    for (int k = t; k < NUM_K; k += 256) {
        float ncs = 0.99f * ecs[k] + 0.01f * counts[k];
        out[O_CS + k] = ncs;
        local += ncs;
    }
    __shared__ float red[256];
    red[t] = local;
    __syncthreads();
    for (int s = 128; s > 0; s >>= 1) {
        if (t < s) red[t] += red[t + s];
        __syncthreads();
    }
    if (t == 0) {
        nptr[0] = red[0];
        out[O_LOSS] = 0.25f * loss_acc[0] / 4194304.0f;
    }
}

__global__ void __launch_bounds__(256)
finalize_w(const float* __restrict__ ema_w, const float* __restrict__ dw,
           float* __restrict__ out, const float* __restrict__ nptr) {
    int e = blockIdx.x * 256 + threadIdx.x;
    int k = e >> 6;
    float n = nptr[0];
    float ncs = out[O_CS + k];
    float cs = (ncs + 1e-5f) / (n + NUM_K * 1e-5f) * n;
    float ew = 0.99f * ema_w[e] + 0.01f * dw[e];
    out[O_EW + e] = ew;
    out[O_W + e] = ew / cs;
}

extern "C" void kernel_launch(void* const* d_in, const int* in_sizes, int n_in,
                              void* d_out, int out_size, void* d_ws, size_t ws_size,
                              hipStream_t stream) {
    const float* x     = (const float*)d_in[0];
    const float* w     = (const float*)d_in[1];
    const float* ecs   = (const float*)d_in[2];
    const float* ema_w = (const float*)d_in[3];
    float* out = (float*)d_out;
    float* ws  = (float*)d_ws;

    float* wsq    = ws + W_WSQ;
    int*   bidx   = (int*)(ws + W_BIDX);
    float* counts = ws + W_CNT;
    float* loss_a = ws + W_LOSS;
    float* nptr   = ws + W_N;
    int*   rcnt   = (int*)(ws + W_RCNT);
    float* dw     = ws + W_DW;
    int*   rlist  = (int*)(ws + W_DW);     // overlays dw; dead before dw is zeroed

    // bf16 hi/lo codebook scratch lives in O_Q (fully overwritten by assign later)
    __bf16* wh = (__bf16*)out;             // 512 KB
    __bf16* wl = wh + NUM_K * CDIM;        // 512 KB

    hipMemsetAsync(counts, 0, 4099 * sizeof(float), stream);   // counts+loss+n+rcnt

    prep_kernel<<<NUM_K / 4, 256, 0, stream>>>(w, wsq, wh, wl);
    argmin_mfma<<<NVEC / 128, 256, 0, stream>>>(x, wh, wl, wsq, bidx, rcnt, rlist);
    rescue_kernel<<<256, 256, 0, stream>>>(x, w, wsq, bidx, rcnt, rlist);

    hipMemsetAsync(dw, 0, (size_t)CHW * sizeof(float), stream);  // after rlist is dead

    assign_kernel<<<NVEC / 64, 256, 0, stream>>>(x, w, bidx, out, counts, dw, loss_a);
    finalize_cs<<<1, 256, 0, stream>>>(ecs, counts, out, loss_a, nptr);
    finalize_w<<<CHW / 256, 256, 0, stream>>>(ema_w, dw, out, nptr);
}

// Round 6
// 281.948 us; speedup vs baseline: 2.2055x; 1.1039x over previous
//
#include <hip/hip_runtime.h>

#define NUM_K   4096
#define CDIM    64
#define HWDIM   4096            // 64*64
#define NVEC    65536           // 16 * 64 * 64
#define CHW     (CDIM * HWDIM)  // 262144
#define KT      32              // codes per k-tile
#define NKT_SL  64              // k-tiles per slice (2048 codes)
#define TAUH    2e-3f           // rescue margin on s/2 scale (validated r4/r5)
#define XSTR    66              // xs stride in bf16 (33 dwords, odd -> conflict-free writes)

// ---- output layout (floats, concatenated in reference return order) ----
#define O_Q     0               // quantized_ste  [16,64,64,64] = 4194304
#define O_LOSS  4194304         // scalar
#define O_IDX   4194305         // encoding_indices [16,64,64] = 65536 (as float)
#define O_W     4259841         // new_weight   [4096,64] = 262144
#define O_CS    4521985         // new_cluster_size [4096]
#define O_EW    4526081         // new_ema_w    [4096,64] = 262144

// ---- workspace layout (floats) ----
#define W_WSQ    0               // 4096
#define W_BIDX   4096            // best idx int[65536]
#define W_CNT    69632           // counts[4096] + loss + n + rcnt (zeroed by prep)
#define W_LOSS   73728
#define W_N      73729
#define W_RCNT   73730
#define W_KEY    73732           // u64 keys [2][65536] = 262144 floats (8B-aligned)
#define W_DW     73732           // dw [262144] overlays keys (dead after combine)
#define W_B2     335876          // float b2 [2][65536]
// high-water: 466948 floats = 1.87 MB (< 2.13 MB proven in r2)

typedef unsigned long long u64;
typedef __bf16 bf16x8 __attribute__((ext_vector_type(8)));
typedef __bf16 bf16x2 __attribute__((ext_vector_type(2)));
typedef float  f32x4  __attribute__((ext_vector_type(4)));

__device__ __forceinline__ unsigned f2ord(float f) {
    unsigned u = __float_as_uint(f);
    return (u & 0x80000000u) ? ~u : (u | 0x80000000u);  // monotone for all finite floats
}
__device__ __forceinline__ float ord2f(unsigned u) {
    return (u & 0x80000000u) ? __uint_as_float(u & 0x7FFFFFFFu) : __uint_as_float(~u);
}

// Per codebook row: wsq (fp32, exact) + bf16 hi/lo split copies. Also zeroes
// counts/loss/n/rcnt (replaces a memset dispatch).
__global__ void __launch_bounds__(256)
prep_kernel(const float* __restrict__ w, float* __restrict__ wsq,
            __bf16* __restrict__ wh, __bf16* __restrict__ wl,
            float* __restrict__ zero_area) {
    int gid = blockIdx.x * 256 + threadIdx.x;
    if (gid < 4099) zero_area[gid] = 0.f;      // counts[4096]+loss+n+rcnt
    int wv = threadIdx.x >> 6, lane = threadIdx.x & 63;
    int row = blockIdx.x * 4 + wv;
    float v = w[row * CDIM + lane];
    __bf16 h = (__bf16)v;
    __bf16 l = (__bf16)(v - (float)h);         // v - hi exact in fp32
    wh[row * CDIM + lane] = h;
    wl[row * CDIM + lane] = l;
    float sq = v * v;
#pragma unroll
    for (int m = 1; m < 64; m <<= 1) sq += __shfl_xor(sq, m, 64);
    if (lane == 0) wsq[row] = sq;
}

// Fused bf16x3-split MFMA GEMM + argmin, K-split into 2 slices (grid.y).
// Block = 128 vectors; LDS overlay: xs staging (33.8 KB) is freed after A-frags
// are register-resident, then the same LDS holds the double-buffered 32-code
// B tile (16 KB). High-water 33.8 KB -> 4 blocks/CU, matching grid 1024.
// A-frags hold -x (hi/lo), acc init = wsq/2 => MFMA output IS s/2.
__global__ void __launch_bounds__(256, 4)
argmin_mfma(const float* __restrict__ x,
            const __bf16* __restrict__ wh_g, const __bf16* __restrict__ wl_g,
            const float* __restrict__ wsq_g,
            u64* __restrict__ keys, float* __restrict__ b2s) {
    extern __shared__ __bf16 smem[];           // 33792 B
    __bf16* xs_h = smem;                       // [128*66]
    __bf16* xs_l = smem + 128 * XSTR;          // [128*66]
    __bf16* bs   = smem;                       // overlay: [2][4096] after xs is dead

    int t = threadIdx.x, wv = t >> 6, lane = t & 63;
    int n0 = blockIdx.x * 128;
    int b = n0 >> 12, hw0 = n0 & (HWDIM - 1);
    int kbase = blockIdx.y * (NUM_K / 2);
    int slice = blockIdx.y;

    // 1) stage -x hi/lo; paired bf16x2 writes, lane-stride 33 dwords -> conflict-free
#pragma unroll
    for (int half = 0; half < 2; ++half) {
        int i = half * 64 + lane;
        const float* xb = x + b * CHW + hw0 + i;
#pragma unroll
        for (int j = 0; j < 8; ++j) {
            int c0 = wv * 16 + j * 2;
            float v0 = -xb[c0 * HWDIM];
            float v1 = -xb[(c0 + 1) * HWDIM];
            __bf16 h0 = (__bf16)v0, h1 = (__bf16)v1;
            bf16x2 hh = {h0, h1};
            bf16x2 ll = {(__bf16)(v0 - (float)h0), (__bf16)(v1 - (float)h1)};
            *(bf16x2*)(xs_h + i * XSTR + c0) = hh;
            *(bf16x2*)(xs_l + i * XSTR + c0) = ll;
        }
    }
    __syncthreads();

    int nn = lane & 15, q4 = lane >> 4;
    // 2) A-frags -> registers (one-time; uint loads since stride 66 is 4B-aligned only)
    bf16x8 ah[2][2], al[2][2];
#pragma unroll
    for (int m = 0; m < 2; ++m) {
        int id = wv * 32 + m * 16 + nn;
#pragma unroll
        for (int ch = 0; ch < 2; ++ch) {
            union { unsigned u[4]; bf16x8 v; } th, tl;
            const unsigned* ph = (const unsigned*)(xs_h + id * XSTR + (q4 + ch * 4) * 8);
            const unsigned* pl = (const unsigned*)(xs_l + id * XSTR + (q4 + ch * 4) * 8);
#pragma unroll
            for (int jj = 0; jj < 4; ++jj) { th.u[jj] = ph[jj]; tl.u[jj] = pl[jj]; }
            ah[m][ch] = th.v; al[m][ch] = tl.v;
        }
    }
    __syncthreads();   // all waves done reading xs -> LDS reusable

    // B staging map: thread t <-> (code = s*16+r, chunk j), r=t&15, j=(t>>4)&7,
    // s=t>>7; LDS dst = t*8 elems (hi) / 2048+t*8 (lo) -> consecutive 16B,
    // conflict-free writes; reads at (chunk*16+code)*8 -> consecutive 16B.
    int sr = t & 15, sj = (t >> 4) & 7, ss = (t >> 7) & 1;
    long goff = (long)(ss * 16 + sr) * 64 + sj * 8;

    // 3) stage B tile 0 into buf 0 (overlays xs region)
    *(bf16x8*)(bs + t * 8)        = *(const bf16x8*)(wh_g + kbase * 64 + goff);
    *(bf16x8*)(bs + 2048 + t * 8) = *(const bf16x8*)(wl_g + kbase * 64 + goff);
    __syncthreads();

    float b1[8], b2[8]; int i1[8];
#pragma unroll
    for (int s = 0; s < 8; ++s) { b1[s] = 3.4e38f; b2[s] = 3.4e38f; i1[s] = 0; }

    for (int kt = 0; kt < NKT_SL; ++kt) {
        __bf16* base = bs + (kt & 1) * 4096;
        bf16x8 st0, st1;
        bool pre = (kt + 1 < NKT_SL);
        if (pre) {   // global loads for next tile; latency spans the MFMA block
            long g = (long)(kbase + (kt + 1) * KT) * 64 + goff;
            st0 = *(const bf16x8*)(wh_g + g);
            st1 = *(const bf16x8*)(wl_g + g);
        }

        int k0 = kbase + kt * KT;
        float wA = 0.5f * wsq_g[k0 + nn];      // 16 KB table, L1-hot
        float wB = 0.5f * wsq_g[k0 + 16 + nn];

        int o1 = (q4 * 16 + nn) * 8, o2 = ((q4 + 4) * 16 + nn) * 8;
        bf16x8 bh0A = *(const bf16x8*)(base + o1);
        bf16x8 bh1A = *(const bf16x8*)(base + o2);
        bf16x8 bh0B = *(const bf16x8*)(base + 1024 + o1);
        bf16x8 bh1B = *(const bf16x8*)(base + 1024 + o2);
        bf16x8 bl0A = *(const bf16x8*)(base + 2048 + o1);
        bf16x8 bl1A = *(const bf16x8*)(base + 2048 + o2);
        bf16x8 bl0B = *(const bf16x8*)(base + 3072 + o1);
        bf16x8 bl1B = *(const bf16x8*)(base + 3072 + o2);

#pragma unroll
        for (int m = 0; m < 2; ++m) {
            f32x4 accA = {wA, wA, wA, wA};     // acc = wsq/2 - dot == s/2
            f32x4 accB = {wB, wB, wB, wB};
            accA = __builtin_amdgcn_mfma_f32_16x16x32_bf16(ah[m][0], bh0A, accA, 0, 0, 0);
            accA = __builtin_amdgcn_mfma_f32_16x16x32_bf16(ah[m][1], bh1A, accA, 0, 0, 0);
            accA = __builtin_amdgcn_mfma_f32_16x16x32_bf16(al[m][0], bh0A, accA, 0, 0, 0);
            accA = __builtin_amdgcn_mfma_f32_16x16x32_bf16(al[m][1], bh1A, accA, 0, 0, 0);
            accA = __builtin_amdgcn_mfma_f32_16x16x32_bf16(ah[m][0], bl0A, accA, 0, 0, 0);
            accA = __builtin_amdgcn_mfma_f32_16x16x32_bf16(ah[m][1], bl1A, accA, 0, 0, 0);
            accB = __builtin_amdgcn_mfma_f32_16x16x32_bf16(ah[m][0], bh0B, accB, 0, 0, 0);
            accB = __builtin_amdgcn_mfma_f32_16x16x32_bf16(ah[m][1], bh1B, accB, 0, 0, 0);
            accB = __builtin_amdgcn_mfma_f32_16x16x32_bf16(al[m][0], bh0B, accB, 0, 0, 0);
            accB = __builtin_amdgcn_mfma_f32_16x16x32_bf16(al[m][1], bh1B, accB, 0, 0, 0);
            accB = __builtin_amdgcn_mfma_f32_16x16x32_bf16(ah[m][0], bl0B, accB, 0, 0, 0);
            accB = __builtin_amdgcn_mfma_f32_16x16x32_bf16(ah[m][1], bl1B, accB, 0, 0, 0);
#pragma unroll
            for (int r = 0; r < 4; ++r) {
                float sa = accA[r], sb = accB[r];        // codes k0+nn, k0+16+nn
                float lo = fminf(sa, sb), hi = fmaxf(sa, sb);
                int   il = (sb < sa) ? (k0 + 16 + nn) : (k0 + nn);  // tie -> lower k
                int   s8 = m * 4 + r;
                b2[s8] = fminf(fminf(b2[s8], hi), fmaxf(b1[s8], lo));
                if (lo < b1[s8]) i1[s8] = il;            // strict < => first-min in k
                b1[s8] = fminf(b1[s8], lo);
            }
        }
        if (pre) {
            __bf16* nb = bs + ((kt + 1) & 1) * 4096;
            *(bf16x8*)(nb + t * 8)        = st0;
            *(bf16x8*)(nb + 2048 + t * 8) = st1;
        }
        __syncthreads();
    }

    // cross-lane merge over the 16 code-classes (lanes sharing q4)
#pragma unroll
    for (int msk = 1; msk < 16; msk <<= 1) {
#pragma unroll
        for (int s = 0; s < 8; ++s) {
            float ob1 = __shfl_xor(b1[s], msk, 64);
            float ob2 = __shfl_xor(b2[s], msk, 64);
            int   oi1 = __shfl_xor(i1[s], msk, 64);
            b2[s] = fminf(fminf(b2[s], ob2), fmaxf(b1[s], ob1));
            if (ob1 < b1[s]) i1[s] = oi1;    // exact cross-lane ties get rescued anyway
            b1[s] = fminf(b1[s], ob1);
        }
    }
    if (nn == 0) {
#pragma unroll
        for (int s = 0; s < 8; ++s) {
            int m = s >> 2, r = s & 3;
            int v = n0 + wv * 32 + m * 16 + q4 * 4 + r;
            keys[slice * NVEC + v] = ((u64)f2ord(b1[s]) << 32) | (unsigned)i1[s];
            b2s[slice * NVEC + v]  = b2[s];
        }
    }
}

// Merge the 2 K-slices: final best idx + rescue flag from the union's margin.
__global__ void __launch_bounds__(256)
combine_kernel(const u64* __restrict__ keys, const float* __restrict__ b2s,
               int* __restrict__ best_idx, int* __restrict__ rcnt,
               int* __restrict__ rlist) {
    int n = blockIdx.x * 256 + threadIdx.x;
    u64 ka = keys[n], kb = keys[NVEC + n];
    u64 km = ka < kb ? ka : kb;          // equal score -> lower idx (slice 0) wins
    best_idx[n] = (int)(km & 0xFFFFFFFFu);
    float a1 = ord2f((unsigned)(ka >> 32));
    float c1 = ord2f((unsigned)(kb >> 32));
    float lo = fminf(a1, c1), hi = fmaxf(a1, c1);
    float m2 = fminf(fminf(b2s[n], b2s[NVEC + n]), hi);   // union second-best
    if (m2 - lo < TAUH) {
        int p = atomicAdd(rcnt, 1);
        rlist[p] = n;
    }
}

// Exact fp32 re-argmin for flagged (near-tie) vectors.
__global__ void __launch_bounds__(256)
rescue_kernel(const float* __restrict__ x, const float* __restrict__ w,
              const float* __restrict__ wsq, int* __restrict__ best_idx,
              const int* __restrict__ rcnt, const int* __restrict__ rlist) {
    __shared__ float xv[CDIM];
    __shared__ u64 rk[256];
    int t = threadIdx.x;
    int cnt = *rcnt;
    for (int i = blockIdx.x; i < cnt; i += gridDim.x) {
        int n = rlist[i];
        int b = n >> 12, hw = n & (HWDIM - 1);
        if (t < CDIM) xv[t] = x[b * CHW + t * HWDIM + hw];
        __syncthreads();
        u64 local = ~0ull;
        for (int k = t; k < NUM_K; k += 256) {
            const float* wr = w + k * CDIM;
            float d0 = 0.f, d1 = 0.f, d2 = 0.f, d3 = 0.f;
#pragma unroll
            for (int c = 0; c < CDIM; c += 4) {
                d0 = fmaf(xv[c + 0], wr[c + 0], d0);
                d1 = fmaf(xv[c + 1], wr[c + 1], d1);
                d2 = fmaf(xv[c + 2], wr[c + 2], d2);
                d3 = fmaf(xv[c + 3], wr[c + 3], d3);
            }
            float s = fmaf((d0 + d1) + (d2 + d3), -2.0f, wsq[k]);
            u64 key = ((u64)f2ord(s) << 32) | (unsigned)k;   // lower k wins ties
            local = local < key ? local : key;
        }
        rk[t] = local;
        __syncthreads();
        for (int s = 128; s > 0; s >>= 1) {
            if (t < s) rk[t] = rk[t] < rk[t + s] ? rk[t] : rk[t + s];
            __syncthreads();
        }
        if (t == 0) best_idx[n] = (int)(rk[0] & 0xFFFFFFFFu);
        __syncthreads();
    }
}

// Gather quantized, STE output, loss partials, histogram + coalesced dw scatter.
__global__ void __launch_bounds__(256)
assign_kernel(const float* __restrict__ x, const float* __restrict__ w,
              const int* __restrict__ best_idx,
              float* __restrict__ out, float* __restrict__ counts,
              float* __restrict__ dw, float* __restrict__ loss_acc) {
    __shared__ float xs[64][CDIM + 1];
    __shared__ int   sidx[64];
    __shared__ float red[256];

    int t  = threadIdx.x;
    int n0 = blockIdx.x * 64;
    int b  = n0 >> 12;
    int hw0 = n0 & (HWDIM - 1);
    const float* xbase = x + b * CHW + hw0;

    if (t < 64) {
        int idx = best_idx[n0 + t];
        sidx[t] = idx;
        out[O_IDX + n0 + t] = (float)idx;
        atomicAdd(&counts[idx], 1.0f);
    }

    int lane = t & 63, wv = t >> 6;
#pragma unroll
    for (int j = 0; j < 16; ++j) {
        int c = wv + j * 4;
        xs[lane][c] = xbase[c * HWDIM + lane];
    }
    __syncthreads();

    float lsum = 0.f;
#pragma unroll
    for (int j = 0; j < 16; ++j) {
        int c = wv + j * 4;
        float xv = xs[lane][c];
        float qv = w[sidx[lane] * CDIM + c];
        float d = qv - xv;
        out[O_Q + b * CHW + c * HWDIM + hw0 + lane] = xv + d;
        lsum = fmaf(d, d, lsum);
    }
    red[t] = lsum;
    __syncthreads();
    for (int s = 128; s > 0; s >>= 1) {
        if (t < s) red[t] += red[t + s];
        __syncthreads();
    }
    if (t == 0) atomicAdd(loss_acc, red[0]);

    for (int i = 0; i < 16; ++i) {
        int nl = wv * 16 + i;
        atomicAdd(&dw[sidx[nl] * CDIM + lane], xs[nl][lane]);  // wave-coalesced row
    }
}

__global__ void __launch_bounds__(256)
finalize_cs(const float* __restrict__ ecs, const float* __restrict__ counts,
            float* __restrict__ out, const float* __restrict__ loss_acc,
            float* __restrict__ nptr) {
    int t = threadIdx.x;
    float local = 0.f;
    for (int k = t; k < NUM_K; k += 256) {
        float ncs = 0.99f * ecs[k] + 0.01f * counts[k];
        out[O_CS + k] = ncs;
        local += ncs;
    }
    __shared__ float red[256];
    red[t] = local;
    __syncthreads();
    for (int s = 128; s > 0; s >>= 1) {
        if (t < s) red[t] += red[t + s];
        __syncthreads();
    }
    if (t == 0) {
        nptr[0] = red[0];
        out[O_LOSS] = 0.25f * loss_acc[0] / 4194304.0f;
    }
}

__global__ void __launch_bounds__(256)
finalize_w(const float* __restrict__ ema_w, const float* __restrict__ dw,
           float* __restrict__ out, const float* __restrict__ nptr) {
    int e = blockIdx.x * 256 + threadIdx.x;
    int k = e >> 6;
    float n = nptr[0];
    float ncs = out[O_CS + k];
    float cs = (ncs + 1e-5f) / (n + NUM_K * 1e-5f) * n;
    float ew = 0.99f * ema_w[e] + 0.01f * dw[e];
    out[O_EW + e] = ew;
    out[O_W + e] = ew / cs;
}

extern "C" void kernel_launch(void* const* d_in, const int* in_sizes, int n_in,
                              void* d_out, int out_size, void* d_ws, size_t ws_size,
                              hipStream_t stream) {
    const float* x     = (const float*)d_in[0];
    const float* w     = (const float*)d_in[1];
    const float* ecs   = (const float*)d_in[2];
    const float* ema_w = (const float*)d_in[3];
    float* out = (float*)d_out;
    float* ws  = (float*)d_ws;

    float* wsq    = ws + W_WSQ;
    int*   bidx   = (int*)(ws + W_BIDX);
    float* counts = ws + W_CNT;
    float* loss_a = ws + W_LOSS;
    float* nptr   = ws + W_N;
    int*   rcnt   = (int*)(ws + W_RCNT);
    u64*   keys   = (u64*)(ws + W_KEY);
    float* b2s    = ws + W_B2;
    float* dw     = ws + W_DW;             // overlays keys (dead after combine)

    // scratch in the O_Q output region (overwritten by assign later):
    // wh/wl bf16 codebook = floats [0, 262144); rlist = floats [262144, 327680)
    __bf16* wh = (__bf16*)out;
    __bf16* wl = wh + NUM_K * CDIM;
    int* rlist = (int*)(out + 262144);

    prep_kernel<<<NUM_K / 4, 256, 0, stream>>>(w, wsq, wh, wl, counts);
    argmin_mfma<<<dim3(NVEC / 128, 2), 256, 33792, stream>>>(x, wh, wl, wsq, keys, b2s);
    combine_kernel<<<NVEC / 256, 256, 0, stream>>>(keys, b2s, bidx, rcnt, rlist);
    rescue_kernel<<<256, 256, 0, stream>>>(x, w, wsq, bidx, rcnt, rlist);

    hipMemsetAsync(dw, 0, (size_t)CHW * sizeof(float), stream);  // keys dead now

    assign_kernel<<<NVEC / 64, 256, 0, stream>>>(x, w, bidx, out, counts, dw, loss_a);
    finalize_cs<<<1, 256, 0, stream>>>(ecs, counts, out, loss_a, nptr);
    finalize_w<<<CHW / 256, 256, 0, stream>>>(ema_w, dw, out, nptr);
}

// Round 8
// 274.568 us; speedup vs baseline: 2.2648x; 1.0269x over previous
//
#include <hip/hip_runtime.h>

#define NUM_K   4096
#define CDIM    64
#define HWDIM   4096            // 64*64
#define NVEC    65536           // 16 * 64 * 64
#define CHW     (CDIM * HWDIM)  // 262144
#define KT      32              // codes per k-tile
#define NKT_SL  64              // k-tiles per slice (2048 codes)
// rescue margin on biased s/2 scale: bf16-split budget 2e-3 (validated r4-r6)
// + 7-bit mask granularity q<=3.9e-3 (scores < 512) + slack
#define TAUH    6e-3f
#define SBIAS   128.0f          // score bias: s' = 128 + (wsq - 2 x.w)/2 > 0 always
#define XSTR    66              // xs stride in bf16 (33 dwords, odd -> conflict-free)

// ---- output layout (floats, concatenated in reference return order) ----
#define O_Q     0               // quantized_ste  [16,64,64,64] = 4194304
#define O_LOSS  4194304         // scalar
#define O_IDX   4194305         // encoding_indices [16,64,64] = 65536 (as float)
#define O_W     4259841         // new_weight   [4096,64] = 262144
#define O_CS    4521985         // new_cluster_size [4096]
#define O_EW    4526081         // new_ema_w    [4096,64] = 262144

// ---- workspace layout (floats) ----
#define W_WSQ    0               // wsq/2 + SBIAS [4096]
#define W_BIDX   4096            // best idx int[65536]
#define W_CNT    69632           // counts[4096] + loss + esum + rcnt (zeroed by prep)
#define W_LOSS   73728
#define W_ESUM   73729           // sum(ema_cluster_size)
#define W_RCNT   73730
#define W_KEY    73732           // u64 keys [2][65536] = 262144 floats (8B-aligned)
#define W_DW     73732           // dw [262144] overlays keys (keys dead after combine)
#define W_B2     335876          // float b2 [2][65536]
// high-water: 466948 floats = 1.87 MB

typedef unsigned long long u64;
typedef __bf16 bf16x8 __attribute__((ext_vector_type(8)));
typedef __bf16 bf16x2 __attribute__((ext_vector_type(2)));
typedef float  f32x4  __attribute__((ext_vector_type(4)));

__device__ __forceinline__ unsigned f2ord(float f) {
    unsigned u = __float_as_uint(f);
    return (u & 0x80000000u) ? ~u : (u | 0x80000000u);
}
__device__ __forceinline__ unsigned umn(unsigned a, unsigned b) { return a < b ? a : b; }
__device__ __forceinline__ unsigned umx(unsigned a, unsigned b) { return a > b ? a : b; }

// Per codebook row: biased wsq/2 + SBIAS (fp32) + bf16 hi/lo split copies.
// Also zeroes counts/loss/esum/rcnt (replaces a memset dispatch).
// The SBIAS makes every tracked score strictly positive (best scores land in
// ~[96,200]) so RAW FLOAT BITS are u32-order-monotone — r7's raw-bit compare
// without the bias broke on negative scores (s/2 = wsq/2 - x.w can be < 0
// since the per-vector ||x||^2 term is dropped).
__global__ void __launch_bounds__(256)
prep_kernel(const float* __restrict__ w, float* __restrict__ wsqh,
            __bf16* __restrict__ wh, __bf16* __restrict__ wl,
            float* __restrict__ zero_area) {
    int gid = blockIdx.x * 256 + threadIdx.x;
    if (gid < 4099) zero_area[gid] = 0.f;      // counts[4096]+loss+esum+rcnt
    int wv = threadIdx.x >> 6, lane = threadIdx.x & 63;
    int row = blockIdx.x * 4 + wv;
    float v = w[row * CDIM + lane];
    __bf16 h = (__bf16)v;
    __bf16 l = (__bf16)(v - (float)h);         // v - hi exact in fp32
    wh[row * CDIM + lane] = h;
    wl[row * CDIM + lane] = l;
    float sq = v * v;
#pragma unroll
    for (int m = 1; m < 64; m <<= 1) sq += __shfl_xor(sq, m, 64);
    if (lane == 0) wsqh[row] = 0.5f * sq + SBIAS;
}

// Fused bf16x3-split MFMA GEMM + argmin, K-split into 2 slices (grid.y).
// Biased scores are strictly positive -> raw float bits order-monotone; the
// in-loop top-2 runs on packed u32 keys (score & ~0x7F) | tag, tag = kt*2+half
// (nn implicit per lane; code = (kbase+nn) + tag*16). 7 VALU per code-pair.
// Masked/exact ties => margin 0 => rescued, so first-min semantics hold.
__global__ void __launch_bounds__(256, 4)
argmin_mfma(const float* __restrict__ x,
            const __bf16* __restrict__ wh_g, const __bf16* __restrict__ wl_g,
            const float* __restrict__ wsqh_g,
            u64* __restrict__ keys, float* __restrict__ b2s) {
    extern __shared__ __bf16 smem[];           // 33792 B
    __bf16* xs_h = smem;                       // [128*66]
    __bf16* xs_l = smem + 128 * XSTR;
    __bf16* bs   = smem;                       // overlay: [2][4096] after xs is dead

    int t = threadIdx.x, wv = t >> 6, lane = t & 63;
    int n0 = blockIdx.x * 128;
    int b = n0 >> 12, hw0 = n0 & (HWDIM - 1);
    int kbase = blockIdx.y * (NUM_K / 2);
    int slice = blockIdx.y;

    // 1) stage -x hi/lo; paired bf16x2 writes, lane-stride 33 dwords -> conflict-free
#pragma unroll
    for (int half = 0; half < 2; ++half) {
        int i = half * 64 + lane;
        const float* xb = x + b * CHW + hw0 + i;
#pragma unroll
        for (int j = 0; j < 8; ++j) {
            int c0 = wv * 16 + j * 2;
            float v0 = -xb[c0 * HWDIM];
            float v1 = -xb[(c0 + 1) * HWDIM];
            __bf16 h0 = (__bf16)v0, h1 = (__bf16)v1;
            bf16x2 hh = {h0, h1};
            bf16x2 ll = {(__bf16)(v0 - (float)h0), (__bf16)(v1 - (float)h1)};
            *(bf16x2*)(xs_h + i * XSTR + c0) = hh;
            *(bf16x2*)(xs_l + i * XSTR + c0) = ll;
        }
    }
    __syncthreads();

    int nn = lane & 15, q4 = lane >> 4;
    // 2) A-frags -> registers (one-time)
    bf16x8 ah[2][2], al[2][2];
#pragma unroll
    for (int m = 0; m < 2; ++m) {
        int id = wv * 32 + m * 16 + nn;
#pragma unroll
        for (int ch = 0; ch < 2; ++ch) {
            union { unsigned u[4]; bf16x8 v; } th, tl;
            const unsigned* ph = (const unsigned*)(xs_h + id * XSTR + (q4 + ch * 4) * 8);
            const unsigned* pl = (const unsigned*)(xs_l + id * XSTR + (q4 + ch * 4) * 8);
#pragma unroll
            for (int jj = 0; jj < 4; ++jj) { th.u[jj] = ph[jj]; tl.u[jj] = pl[jj]; }
            ah[m][ch] = th.v; al[m][ch] = tl.v;
        }
    }
    __syncthreads();   // all waves done reading xs -> LDS reusable for B tiles

    // B staging map: thread t writes LDS bytes t*16 (consecutive, conflict-free);
    // reads at (chunk*16+code)*8 elems -> consecutive 16B per lane group.
    int sr = t & 15, sj = (t >> 4) & 7, ss = (t >> 7) & 1;
    long goff = (long)(ss * 16 + sr) * 64 + sj * 8;

    *(bf16x8*)(bs + t * 8)        = *(const bf16x8*)(wh_g + kbase * 64 + goff);
    *(bf16x8*)(bs + 2048 + t * 8) = *(const bf16x8*)(wl_g + kbase * 64 + goff);
    __syncthreads();

    unsigned b1k[8], b2k[8];
#pragma unroll
    for (int s = 0; s < 8; ++s) { b1k[s] = 0xFFFFFFFFu; b2k[s] = 0xFFFFFFFFu; }

    for (int kt = 0; kt < NKT_SL; ++kt) {
        __bf16* base = bs + (kt & 1) * 4096;
        bf16x8 st0, st1;
        bool pre = (kt + 1 < NKT_SL);
        if (pre) {   // global loads for next tile; latency spans the MFMA block
            long g = (long)(kbase + (kt + 1) * KT) * 64 + goff;
            st0 = *(const bf16x8*)(wh_g + g);
            st1 = *(const bf16x8*)(wl_g + g);
        }

        int k0 = kbase + kt * KT;
        float wA = wsqh_g[k0 + nn];            // biased table, L1-hot
        float wB = wsqh_g[k0 + 16 + nn];
        unsigned tA = (unsigned)(kt * 2), tB = (unsigned)(kt * 2 + 1);

        int o1 = (q4 * 16 + nn) * 8, o2 = ((q4 + 4) * 16 + nn) * 8;
        bf16x8 bh0A = *(const bf16x8*)(base + o1);
        bf16x8 bh1A = *(const bf16x8*)(base + o2);
        bf16x8 bh0B = *(const bf16x8*)(base + 1024 + o1);
        bf16x8 bh1B = *(const bf16x8*)(base + 1024 + o2);
        bf16x8 bl0A = *(const bf16x8*)(base + 2048 + o1);
        bf16x8 bl1A = *(const bf16x8*)(base + 2048 + o2);
        bf16x8 bl0B = *(const bf16x8*)(base + 3072 + o1);
        bf16x8 bl1B = *(const bf16x8*)(base + 3072 + o2);

#pragma unroll
        for (int m = 0; m < 2; ++m) {
            f32x4 accA = {wA, wA, wA, wA};     // acc = SBIAS + wsq/2 - dot  (> 0)
            f32x4 accB = {wB, wB, wB, wB};
            accA = __builtin_amdgcn_mfma_f32_16x16x32_bf16(ah[m][0], bh0A, accA, 0, 0, 0);
            accA = __builtin_amdgcn_mfma_f32_16x16x32_bf16(ah[m][1], bh1A, accA, 0, 0, 0);
            accA = __builtin_amdgcn_mfma_f32_16x16x32_bf16(al[m][0], bh0A, accA, 0, 0, 0);
            accA = __builtin_amdgcn_mfma_f32_16x16x32_bf16(al[m][1], bh1A, accA, 0, 0, 0);
            accA = __builtin_amdgcn_mfma_f32_16x16x32_bf16(ah[m][0], bl0A, accA, 0, 0, 0);
            accA = __builtin_amdgcn_mfma_f32_16x16x32_bf16(ah[m][1], bl1A, accA, 0, 0, 0);
            accB = __builtin_amdgcn_mfma_f32_16x16x32_bf16(ah[m][0], bh0B, accB, 0, 0, 0);
            accB = __builtin_amdgcn_mfma_f32_16x16x32_bf16(ah[m][1], bh1B, accB, 0, 0, 0);
            accB = __builtin_amdgcn_mfma_f32_16x16x32_bf16(al[m][0], bh0B, accB, 0, 0, 0);
            accB = __builtin_amdgcn_mfma_f32_16x16x32_bf16(al[m][1], bh1B, accB, 0, 0, 0);
            accB = __builtin_amdgcn_mfma_f32_16x16x32_bf16(ah[m][0], bl0B, accB, 0, 0, 0);
            accB = __builtin_amdgcn_mfma_f32_16x16x32_bf16(ah[m][1], bl1B, accB, 0, 0, 0);
#pragma unroll
            for (int r = 0; r < 4; ++r) {
                unsigned ka = (__float_as_uint(accA[r]) & 0xFFFFFF80u) | tA;  // v_and_or_b32
                unsigned kb = (__float_as_uint(accB[r]) & 0xFFFFFF80u) | tB;
                unsigned lo = umn(ka, kb), hi = umx(ka, kb);
                int s8 = m * 4 + r;
                b2k[s8] = umn(umn(b2k[s8], umx(b1k[s8], lo)), hi);  // min3 fuse
                b1k[s8] = umn(b1k[s8], lo);
            }
        }
        if (pre) {
            __bf16* nb = bs + ((kt + 1) & 1) * 4096;
            *(bf16x8*)(nb + t * 8)        = st0;
            *(bf16x8*)(nb + 2048 + t * 8) = st1;
        }
        __syncthreads();
    }

    // unpack: tag*16 == kt*32 + half*16, so code = (kbase+nn) + tag*16
    float s1[8], sb2[8]; int code[8];
#pragma unroll
    for (int s = 0; s < 8; ++s) {
        s1[s]  = __uint_as_float(b1k[s] & 0xFFFFFF80u);
        sb2[s] = __uint_as_float(b2k[s] & 0xFFFFFF80u);
        code[s] = (kbase + nn) + (int)(b1k[s] & 0x7Fu) * 16;
    }
    // cross-lane merge over the 16 code-classes (lanes sharing q4)
#pragma unroll
    for (int msk = 1; msk < 16; msk <<= 1) {
#pragma unroll
        for (int s = 0; s < 8; ++s) {
            float os1 = __shfl_xor(s1[s], msk, 64);
            float ob2 = __shfl_xor(sb2[s], msk, 64);
            int   oc  = __shfl_xor(code[s], msk, 64);
            sb2[s] = fminf(fminf(sb2[s], ob2), fmaxf(s1[s], os1));
            if (os1 < s1[s]) code[s] = oc;   // exact ties -> margin 0 -> rescued
            s1[s] = fminf(s1[s], os1);
        }
    }
    if (nn == 0) {
#pragma unroll
        for (int s = 0; s < 8; ++s) {
            int m = s >> 2, r = s & 3;
            int v = n0 + wv * 32 + m * 16 + q4 * 4 + r;
            keys[slice * NVEC + v] = ((u64)__float_as_uint(s1[s]) << 32) | (unsigned)code[s];
            b2s[slice * NVEC + v]  = sb2[s];
        }
    }
}

// Merge the 2 K-slices; also reduce sum(ecs) -> esum (needed by finalize).
__global__ void __launch_bounds__(256)
combine_kernel(const u64* __restrict__ keys, const float* __restrict__ b2s,
               const float* __restrict__ ecs, float* __restrict__ esum,
               int* __restrict__ best_idx, int* __restrict__ rcnt,
               int* __restrict__ rlist) {
    int n = blockIdx.x * 256 + threadIdx.x;
    if (n < NUM_K) {                       // blocks 0-15: ecs sum
        float v = ecs[n];
#pragma unroll
        for (int m = 1; m < 64; m <<= 1) v += __shfl_xor(v, m, 64);
        if ((threadIdx.x & 63) == 0) atomicAdd(esum, v);
    }
    u64 ka = keys[n], kb = keys[NVEC + n];
    u64 km = ka < kb ? ka : kb;            // equal score -> lower code (slice 0) wins
    best_idx[n] = (int)(km & 0xFFFFFFFFu);
    float a1 = __uint_as_float((unsigned)(ka >> 32));   // biased scores > 0: bits monotone
    float c1 = __uint_as_float((unsigned)(kb >> 32));
    float lo = fminf(a1, c1), hi = fmaxf(a1, c1);
    float m2 = fminf(fminf(b2s[n], b2s[NVEC + n]), hi); // union second-best
    if (m2 - lo < TAUH) {
        int p = atomicAdd(rcnt, 1);
        rlist[p] = n;
    }
}

// Exact fp32 re-argmin for flagged (near-tie) vectors; also zeroes dw
// (which overlays the now-dead keys array) before assign runs.
__global__ void __launch_bounds__(256)
rescue_kernel(const float* __restrict__ x, const float* __restrict__ w,
              const float* __restrict__ wsqh, int* __restrict__ best_idx,
              const int* __restrict__ rcnt, const int* __restrict__ rlist,
              float* __restrict__ dw) {
    int t = threadIdx.x;
    for (int i = blockIdx.x * 256 + t; i < CHW; i += 256 * 256) dw[i] = 0.f;

    __shared__ float xv[CDIM];
    __shared__ u64 rk[256];
    int cnt = *rcnt;
    for (int i = blockIdx.x; i < cnt; i += gridDim.x) {
        int n = rlist[i];
        int b = n >> 12, hw = n & (HWDIM - 1);
        if (t < CDIM) xv[t] = x[b * CHW + t * HWDIM + hw];
        __syncthreads();
        u64 local = ~0ull;
        for (int k = t; k < NUM_K; k += 256) {
            const float* wr = w + k * CDIM;
            float d0 = 0.f, d1 = 0.f, d2 = 0.f, d3 = 0.f;
#pragma unroll
            for (int c = 0; c < CDIM; c += 4) {
                d0 = fmaf(xv[c + 0], wr[c + 0], d0);
                d1 = fmaf(xv[c + 1], wr[c + 1], d1);
                d2 = fmaf(xv[c + 2], wr[c + 2], d2);
                d3 = fmaf(xv[c + 3], wr[c + 3], d3);
            }
            // biased s/2 scale (wsqh includes SBIAS): ordering identical
            float s = wsqh[k] - ((d0 + d1) + (d2 + d3));
            u64 key = ((u64)f2ord(s) << 32) | (unsigned)k; // lower k wins ties
            local = local < key ? local : key;
        }
        rk[t] = local;
        __syncthreads();
        for (int s = 128; s > 0; s >>= 1) {
            if (t < s) rk[t] = rk[t] < rk[t + s] ? rk[t] : rk[t + s];
            __syncthreads();
        }
        if (t == 0) best_idx[n] = (int)(rk[0] & 0xFFFFFFFFu);
        __syncthreads();
    }
}

// Gather quantized, STE output, loss partials, histogram + coalesced dw scatter.
__global__ void __launch_bounds__(256)
assign_kernel(const float* __restrict__ x, const float* __restrict__ w,
              const int* __restrict__ best_idx,
              float* __restrict__ out, float* __restrict__ counts,
              float* __restrict__ dw, float* __restrict__ loss_acc) {
    __shared__ float xs[64][CDIM + 1];
    __shared__ int   sidx[64];
    __shared__ float red[256];

    int t  = threadIdx.x;
    int n0 = blockIdx.x * 64;
    int b  = n0 >> 12;
    int hw0 = n0 & (HWDIM - 1);
    const float* xbase = x + b * CHW + hw0;

    if (t < 64) {
        int idx = best_idx[n0 + t];
        sidx[t] = idx;
        out[O_IDX + n0 + t] = (float)idx;
        atomicAdd(&counts[idx], 1.0f);
    }

    int lane = t & 63, wv = t >> 6;
#pragma unroll
    for (int j = 0; j < 16; ++j) {
        int c = wv + j * 4;
        xs[lane][c] = xbase[c * HWDIM + lane];
    }
    __syncthreads();

    float lsum = 0.f;
#pragma unroll
    for (int j = 0; j < 16; ++j) {
        int c = wv + j * 4;
        float xv = xs[lane][c];
        float qv = w[sidx[lane] * CDIM + c];
        float d = qv - xv;
        out[O_Q + b * CHW + c * HWDIM + hw0 + lane] = xv + d;
        lsum = fmaf(d, d, lsum);
    }
    red[t] = lsum;
    __syncthreads();
    for (int s = 128; s > 0; s >>= 1) {
        if (t < s) red[t] += red[t + s];
        __syncthreads();
    }
    if (t == 0) atomicAdd(loss_acc, red[0]);

    for (int i = 0; i < 16; ++i) {
        int nl = wv * 16 + i;
        atomicAdd(&dw[sidx[nl] * CDIM + lane], xs[nl][lane]);  // wave-coalesced row
    }
}

// One fused elementwise pass over [4096,64]: new_cluster_size, new_ema_w,
// new_weight, loss. n = 0.99*sum(ecs) + 0.01*65536 (counts sum analytically).
__global__ void __launch_bounds__(256)
finalize_all(const float* __restrict__ ecs, const float* __restrict__ counts,
             const float* __restrict__ ema_w, const float* __restrict__ dw,
             const float* __restrict__ loss_acc, const float* __restrict__ esum,
             float* __restrict__ out) {
    int e = blockIdx.x * 256 + threadIdx.x;   // 0..262143
    int k = e >> 6;                            // wave-uniform
    float ncs = 0.99f * ecs[k] + 0.01f * counts[k];
    if ((e & 63) == 0) out[O_CS + k] = ncs;
    if (e == 0) out[O_LOSS] = 0.25f * loss_acc[0] / 4194304.0f;
    float n = 0.99f * esum[0] + 0.01f * 65536.0f;
    float cs = (ncs + 1e-5f) / (n + NUM_K * 1e-5f) * n;
    float ew = 0.99f * ema_w[e] + 0.01f * dw[e];
    out[O_EW + e] = ew;
    out[O_W + e] = ew / cs;
}

extern "C" void kernel_launch(void* const* d_in, const int* in_sizes, int n_in,
                              void* d_out, int out_size, void* d_ws, size_t ws_size,
                              hipStream_t stream) {
    const float* x     = (const float*)d_in[0];
    const float* w     = (const float*)d_in[1];
    const float* ecs   = (const float*)d_in[2];
    const float* ema_w = (const float*)d_in[3];
    float* out = (float*)d_out;
    float* ws  = (float*)d_ws;

    float* wsqh   = ws + W_WSQ;
    int*   bidx   = (int*)(ws + W_BIDX);
    float* counts = ws + W_CNT;
    float* loss_a = ws + W_LOSS;
    float* esum   = ws + W_ESUM;
    int*   rcnt   = (int*)(ws + W_RCNT);
    u64*   keys   = (u64*)(ws + W_KEY);
    float* b2s    = ws + W_B2;
    float* dw     = ws + W_DW;             // overlays keys (dead after combine)

    // scratch in the O_Q output region (overwritten by assign later):
    // wh/wl bf16 codebook = floats [0, 262144); rlist = floats [262144, 327680)
    __bf16* wh = (__bf16*)out;
    __bf16* wl = wh + NUM_K * CDIM;
    int* rlist = (int*)(out + 262144);

    prep_kernel<<<NUM_K / 4, 256, 0, stream>>>(w, wsqh, wh, wl, counts);
    argmin_mfma<<<dim3(NVEC / 128, 2), 256, 33792, stream>>>(x, wh, wl, wsqh, keys, b2s);
    combine_kernel<<<NVEC / 256, 256, 0, stream>>>(keys, b2s, ecs, esum, bidx, rcnt, rlist);
    rescue_kernel<<<256, 256, 0, stream>>>(x, w, wsqh, bidx, rcnt, rlist, dw);
    assign_kernel<<<NVEC / 64, 256, 0, stream>>>(x, w, bidx, out, counts, dw, loss_a);
    finalize_all<<<CHW / 256, 256, 0, stream>>>(ecs, counts, ema_w, dw, loss_a, esum, out);
}